// Round 8
// baseline (36.814 us; speedup 1.0000x reference)
//
#include <hip/hip_runtime.h>

#define NQ 10
#define EMBED 1024

// ---------------------------------------------------------------------------
// Closed-form ev (validated R1-R7, passing at absmax 2e-3):
// conjugate circuit by H^10 -> RX gates become diagonal phases, CNOT ring
// becomes reversed ring sigma.  <Z_q> collapses to a trig polynomial:
//   ev_q = sum_{S subset u_q, T=sigma^T S subset v_q} i^(|T|+|S|)
//          prod_{T} sinA prod_{v\T} cosA * prod_{S} sinB prod_{u\S} cosB
// Odd-parity terms are imaginary and cancel -> filtered at constexpr time.
// ---------------------------------------------------------------------------

constexpr int kPop(int x) { int c = 0; for (int i = 0; i < 10; ++i) c += (x >> i) & 1; return c; }

constexpr int sigma_map(int a) {
    int b = 0;
    for (int i = 0; i < 9; ++i) b |= (((a >> i) & 1) ^ ((a >> (i + 1)) & 1)) << i;
    b |= (((a >> 9) & 1) ^ ((a >> 0) & 1) ^ ((a >> 1) & 1)) << 9;
    return b;
}

#define MAXT 40
struct Terms {
    int nt[NQ];
    int vm[NQ];
    int um[NQ];
    unsigned short tm[NQ][MAXT];
    unsigned short sm[NQ][MAXT];
    float sg[NQ][MAXT];
};

constexpr Terms gen_terms() {
    Terms t{};
    int inv_e[NQ] = {};
    for (int a = 0; a < 1024; ++a) {
        const int s = sigma_map(a);
        for (int q = 0; q < NQ; ++q) if (s == (1 << q)) inv_e[q] = a;
    }
    for (int q = 0; q < NQ; ++q) {
        const int u = inv_e[q];
        int v = 0;
        for (int w = 0; w < NQ; ++w) if ((u >> w) & 1) v ^= inv_e[w];
        t.um[q] = u; t.vm[q] = v;
        int n = 0;
        int S = 0;
        while (true) {
            int T = (((S >> 0) ^ (S >> 9)) & 1)
                  | ((((S >> 0) ^ (S >> 1) ^ (S >> 9)) & 1) << 1);
            for (int j = 2; j < 10; ++j) T |= ((((S >> (j - 1)) ^ (S >> j)) & 1) << j);
            if ((T & ~v) == 0) {
                const int p = kPop(T) + kPop(S);
                if (!(p & 1)) {
                    t.tm[q][n] = (unsigned short)T;
                    t.sm[q][n] = (unsigned short)S;
                    t.sg[q][n] = (p & 2) ? -1.f : 1.f;
                    ++n;
                }
            }
            if (S == u) break;
            S = (S - u) & u;
        }
        t.nt[q] = n;
    }
    return t;
}

constexpr Terms TT = gen_terms();

// ---- DPP full-wave (64-lane) sum on the VALU pipe: no DS traffic ----------
// xor1, xor2, row_half_mirror, row_mirror -> 16-lane sums in all lanes;
// row_bcast15 (rows 1,3) -> 32-sums in lanes 16-31 / 48-63;
// row_bcast31 (row 3)    -> full 64-sum valid in lanes 48-63.
template <int CTRL, int RM>
__device__ __forceinline__ float dppadd(float v) {
    const int s = __builtin_amdgcn_update_dpp(0, __float_as_int(v), CTRL, RM, 0xF, true);
    return v + __int_as_float(s);
}
__device__ __forceinline__ float red64(float v) {
    v = dppadd<0xB1,  0xF>(v);   // quad_perm 1,0,3,2
    v = dppadd<0x4E,  0xF>(v);   // quad_perm 2,3,0,1
    v = dppadd<0x141, 0xF>(v);   // row_half_mirror
    v = dppadd<0x140, 0xF>(v);   // row_mirror
    v = dppadd<0x142, 0xA>(v);   // row_bcast15 -> rows 1,3
    v = dppadd<0x143, 0x8>(v);   // row_bcast31 -> row 3
    return v;
}

// ===========================================================================
// Kernel 1: W1 entirely in registers (40 float4/lane), one wave per row,
// 8 rows/wave, 2-row-deep x prefetch, DPP reduction, tiny LDS for angles.
// ev written into out[row*1024 + q] scratch (K2 reads before overwriting).
// ===========================================================================
extern "C" __global__ __launch_bounds__(512, 2)
void ffq_ev_kernel(const float* __restrict__ x, const float* __restrict__ W1,
                   const float* __restrict__ b1, const float* __restrict__ qw,
                   float* __restrict__ out)
{
    __shared__ float sANG[64][11];      // padded stride 11: conflict-free

    const int tid  = threadIdx.x;
    const int lane = tid & 63;
    const int wv   = tid >> 6;          // 0..7
    const int block0 = blockIdx.x * 64;
    const int wrow0  = block0 + wv * 8; // this wave's first row

    // ---- W1 -> registers: w1r[j][q] = W1 float4 at column (j*64+lane) ----
    const float4* W1v = (const float4*)W1;
    float4 w1r[4][NQ];
    #pragma unroll
    for (int j = 0; j < 4; ++j)
        #pragma unroll
        for (int q = 0; q < NQ; ++q)
            w1r[j][q] = W1v[q * 256 + j * 64 + lane];

    float b1q[NQ];
    #pragma unroll
    for (int w = 0; w < NQ; ++w) b1q[w] = b1[w] + qw[w];

    const float4* Xv = (const float4*)x;

    // ---- prefetch rows 0,1 ----
    float4 xa[4], xb[4];
    #pragma unroll
    for (int j = 0; j < 4; ++j) xa[j] = Xv[(size_t)(wrow0 + 0) * 256 + j * 64 + lane];
    #pragma unroll
    for (int j = 0; j < 4; ++j) xb[j] = Xv[(size_t)(wrow0 + 1) * 256 + j * 64 + lane];

    #pragma unroll
    for (int r = 0; r < 8; ++r) {
        // copy out current row's data (compile-time select), then overwrite
        float4 xc[4];
        #pragma unroll
        for (int j = 0; j < 4; ++j) xc[j] = (r & 1) ? xb[j] : xa[j];
        if (r < 6) {
            #pragma unroll
            for (int j = 0; j < 4; ++j) {
                const float4 nv = Xv[(size_t)(wrow0 + r + 2) * 256 + j * 64 + lane];
                if (r & 1) xb[j] = nv; else xa[j] = nv;
            }
        }

        float acc[NQ];
        #pragma unroll
        for (int q = 0; q < NQ; ++q) acc[q] = 0.f;
        #pragma unroll
        for (int j = 0; j < 4; ++j) {
            #pragma unroll
            for (int q = 0; q < NQ; ++q) {
                acc[q] = fmaf(xc[j].x, w1r[j][q].x, acc[q]);
                acc[q] = fmaf(xc[j].y, w1r[j][q].y, acc[q]);
                acc[q] = fmaf(xc[j].z, w1r[j][q].z, acc[q]);
                acc[q] = fmaf(xc[j].w, w1r[j][q].w, acc[q]);
            }
        }

        // full-wave DPP reduce (result valid in lanes 48-63)
        float racc[NQ];
        #pragma unroll
        for (int q = 0; q < NQ; ++q) racc[q] = red64(acc[q]) + b1q[q];

        if (lane == 48) {
            #pragma unroll
            for (int w = 0; w < NQ; ++w) sANG[wv * 8 + r][w] = racc[w];
        }
    }

    __syncthreads();

    // ---- ev: lane = row (64 rows/block), wave-uniform q-set per wave ----
    {
        const int row = lane;
        float ca[NQ], sa[NQ], cb[NQ], sb[NQ];
        #pragma unroll
        for (int w = 0; w < NQ; ++w) {
            const float A = sANG[row][w];
            ca[w] = __cosf(A); sa[w] = __sinf(A);
            const float B = qw[NQ + w];
            cb[w] = __cosf(B); sb[w] = __sinf(B);
        }
        float* orow = out + (size_t)(block0 + row) * EMBED;
        #define EVQ(QC) do {                                                      \
            float ev = 0.f;                                                       \
            _Pragma("unroll")                                                     \
            for (int k = 0; k < TT.nt[QC]; ++k) {                                 \
                float P = TT.sg[QC][k];                                           \
                _Pragma("unroll")                                                 \
                for (int w = 0; w < NQ; ++w) {                                    \
                    if ((TT.vm[QC] >> w) & 1) P *= ((TT.tm[QC][k] >> w) & 1) ? sa[w] : ca[w]; \
                    if ((TT.um[QC] >> w) & 1) P *= ((TT.sm[QC][k] >> w) & 1) ? sb[w] : cb[w]; \
                }                                                                 \
                ev += P;                                                          \
            }                                                                     \
            orow[QC] = ev;                                                        \
        } while (0)
        switch (wv) {
            case 0: EVQ(0); break;
            case 1: EVQ(9); break;
            case 2: EVQ(7); break;
            case 3: EVQ(8); break;
            case 4: EVQ(5); EVQ(6); break;
            case 5: EVQ(3); EVQ(4); break;
            case 6: EVQ(1); EVQ(2); break;
            default: break;              // wave 7 idle
        }
        #undef EVQ
    }
}

// ===========================================================================
// Kernel 2: out[r][e] = b2[e] + sum_q ev[r][q]*W2[e][q].  Pure write stream.
// ev read from out[r][0..9] (written by K1), staged to LDS behind a barrier
// so no store can precede the reads.
// ===========================================================================
extern "C" __global__ __launch_bounds__(256, 4)
void ffq_out_kernel(const float* __restrict__ W2, const float* __restrict__ b2,
                    float* __restrict__ out)
{
    __shared__ float sev[80];           // 8 rows x 10 q

    const int tid = threadIdx.x;
    const int r0  = blockIdx.x * 8;

    float w2f[40];
    {
        const float4* w2v = (const float4*)(W2 + tid * 40);
        #pragma unroll
        for (int i = 0; i < 10; ++i) {
            float4 v = w2v[i];
            w2f[4*i+0] = v.x; w2f[4*i+1] = v.y; w2f[4*i+2] = v.z; w2f[4*i+3] = v.w;
        }
    }
    const float4 b2v = ((const float4*)b2)[tid];

    if (tid < 80) {
        const int rr = tid / 10;
        const int qq = tid - rr * 10;
        sev[tid] = out[(size_t)(r0 + rr) * EMBED + qq];
    }
    __syncthreads();

    #pragma unroll
    for (int rr = 0; rr < 8; ++rr) {
        float o0 = b2v.x, o1 = b2v.y, o2 = b2v.z, o3 = b2v.w;
        #pragma unroll
        for (int q = 0; q < NQ; ++q) {
            const float e = sev[rr * 10 + q];
            o0 = fmaf(e, w2f[ 0 + q], o0);
            o1 = fmaf(e, w2f[10 + q], o1);
            o2 = fmaf(e, w2f[20 + q], o2);
            o3 = fmaf(e, w2f[30 + q], o3);
        }
        float4 ov = {o0, o1, o2, o3};
        ((float4*)(out + (size_t)(r0 + rr) * EMBED))[tid] = ov;
    }
}

extern "C" void kernel_launch(void* const* d_in, const int* in_sizes, int n_in,
                              void* d_out, int out_size, void* d_ws, size_t ws_size,
                              hipStream_t stream) {
    (void)in_sizes; (void)n_in; (void)d_ws; (void)ws_size; (void)out_size;
    const float* x  = (const float*)d_in[0];
    const float* W1 = (const float*)d_in[1];
    const float* b1 = (const float*)d_in[2];
    const float* qw = (const float*)d_in[3];
    const float* W2 = (const float*)d_in[4];
    const float* b2 = (const float*)d_in[5];
    float* out = (float*)d_out;

    ffq_ev_kernel<<<dim3(256), 512, 0, stream>>>(x, W1, b1, qw, out);
    ffq_out_kernel<<<dim3(2048), 256, 0, stream>>>(W2, b2, out);
}

// Round 9
// 28.272 us; speedup vs baseline: 1.3021x; 1.3021x over previous
//
#include <hip/hip_runtime.h>

#define NQ 10
#define EMBED 1024
#define ROWS_PER_BLOCK 32
#define BLOCK 512

// ---------------------------------------------------------------------------
// Closed-form ev (validated R1-R8, passing at absmax 2e-3):
// conjugate circuit by H^10 -> RX gates become diagonal phases, CNOT ring
// becomes reversed ring sigma.  <Z_q> collapses to a trig polynomial:
//   ev_q = sum_{S subset u_q, T=sigma^T S subset v_q} i^(|T|+|S|)
//          prod_{T} sinA prod_{v\T} cosA * prod_{S} sinB prod_{u\S} cosB
// Odd-parity terms are imaginary and cancel -> filtered at constexpr time.
// ---------------------------------------------------------------------------

constexpr int kPop(int x) { int c = 0; for (int i = 0; i < 10; ++i) c += (x >> i) & 1; return c; }

constexpr int sigma_map(int a) {
    int b = 0;
    for (int i = 0; i < 9; ++i) b |= (((a >> i) & 1) ^ ((a >> (i + 1)) & 1)) << i;
    b |= (((a >> 9) & 1) ^ ((a >> 0) & 1) ^ ((a >> 1) & 1)) << 9;
    return b;
}

#define MAXT 40
struct Terms {
    int nt[NQ];
    int vm[NQ];
    int um[NQ];
    unsigned short tm[NQ][MAXT];
    unsigned short sm[NQ][MAXT];
    float sg[NQ][MAXT];
};

constexpr Terms gen_terms() {
    Terms t{};
    int inv_e[NQ] = {};
    for (int a = 0; a < 1024; ++a) {
        const int s = sigma_map(a);
        for (int q = 0; q < NQ; ++q) if (s == (1 << q)) inv_e[q] = a;
    }
    for (int q = 0; q < NQ; ++q) {
        const int u = inv_e[q];
        int v = 0;
        for (int w = 0; w < NQ; ++w) if ((u >> w) & 1) v ^= inv_e[w];
        t.um[q] = u; t.vm[q] = v;
        int n = 0;
        int S = 0;
        while (true) {
            int T = (((S >> 0) ^ (S >> 9)) & 1)
                  | ((((S >> 0) ^ (S >> 1) ^ (S >> 9)) & 1) << 1);
            for (int j = 2; j < 10; ++j) T |= ((((S >> (j - 1)) ^ (S >> j)) & 1) << j);
            if ((T & ~v) == 0) {
                const int p = kPop(T) + kPop(S);
                if (!(p & 1)) {
                    t.tm[q][n] = (unsigned short)T;
                    t.sm[q][n] = (unsigned short)S;
                    t.sg[q][n] = (p & 2) ? -1.f : 1.f;
                    ++n;
                }
            }
            if (S == u) break;
            S = (S - u) & u;
        }
        t.nt[q] = n;
    }
    return t;
}

constexpr Terms TT = gen_terms();

// ---- DPP 32-lane sum on the VALU pipe (no DS traffic) ---------------------
// After row_bcast15 (rows 1,3): lanes 16-31 hold sum of lanes 0-31,
// lanes 48-63 hold sum of lanes 32-63.  Validated in R6/R7 (passing).
template <int CTRL, int RM>
__device__ __forceinline__ float dppadd(float v) {
    const int s = __builtin_amdgcn_update_dpp(0, __float_as_int(v), CTRL, RM, 0xF, true);
    return v + __int_as_float(s);
}
__device__ __forceinline__ float red32(float v) {
    v = dppadd<0xB1,  0xF>(v);   // quad_perm 1,0,3,2
    v = dppadd<0x4E,  0xF>(v);   // quad_perm 2,3,0,1
    v = dppadd<0x141, 0xF>(v);   // row_half_mirror
    v = dppadd<0x140, 0xF>(v);   // row_mirror
    v = dppadd<0x142, 0xA>(v);   // row_bcast15 -> rows 1,3
    return v;
}

extern "C" __global__ __launch_bounds__(BLOCK, 4)
void ffq_kernel(const float* __restrict__ x, const float* __restrict__ W1,
                const float* __restrict__ b1, const float* __restrict__ qw,
                const float* __restrict__ W2, const float* __restrict__ b2,
                float* __restrict__ out)
{
    __shared__ float sW1[NQ * EMBED];        // 40 KiB
    __shared__ float sCA[ROWS_PER_BLOCK][11];
    __shared__ float sSA[ROWS_PER_BLOCK][11];
    __shared__ float sEVv[ROWS_PER_BLOCK][11];

    const int tid  = threadIdx.x;
    const int lane = tid & 63;
    const int wv   = tid >> 6;          // 0..7
    const int o    = lane & 31;         // k-slice lane within row
    const int g    = lane >> 5;         // group 0..1 (2 rows each)
    const int block0 = blockIdx.x * ROWS_PER_BLOCK;

    // ---- stage W1 into LDS (coalesced float4) ----
    {
        const float4* src = (const float4*)W1;
        float4* dst = (float4*)sW1;
        #pragma unroll
        for (int i = 0; i < 5; ++i) dst[tid + BLOCK * i] = src[tid + BLOCK * i];
    }

    float b1q[NQ];
    #pragma unroll
    for (int w = 0; w < NQ; ++w) b1q[w] = b1[w] + qw[w];

    __syncthreads();

    // ---------- stage 1: 4 rows/wave (2 rows/lane), 32 lanes/row ----------
    {
        const int rloc0 = wv * 4 + g * 2;
        const float4* xr0 = (const float4*)(x + (size_t)(block0 + rloc0) * EMBED);
        const float4* xr1 = (const float4*)(x + (size_t)(block0 + rloc0 + 1) * EMBED);

        // deep MLP: all 16 x loads issued up front
        float4 xv0[8], xv1[8];
        #pragma unroll
        for (int k = 0; k < 8; ++k) xv0[k] = xr0[k * 32 + o];
        #pragma unroll
        for (int k = 0; k < 8; ++k) xv1[k] = xr1[k * 32 + o];

        float acc0[NQ], acc1[NQ];
        #pragma unroll
        for (int q = 0; q < NQ; ++q) { acc0[q] = 0.f; acc1[q] = 0.f; }

        const float4* w1v = (const float4*)sW1;
        #pragma unroll
        for (int k = 0; k < 8; ++k) {
            // half-batches of 5 ds_read_b128 to bound transient VGPR
            float4 wA[5];
            #pragma unroll
            for (int q = 0; q < 5; ++q) wA[q] = w1v[q * 256 + k * 32 + o];
            #pragma unroll
            for (int q = 0; q < 5; ++q) {
                acc0[q] = fmaf(xv0[k].x, wA[q].x, acc0[q]);
                acc0[q] = fmaf(xv0[k].y, wA[q].y, acc0[q]);
                acc0[q] = fmaf(xv0[k].z, wA[q].z, acc0[q]);
                acc0[q] = fmaf(xv0[k].w, wA[q].w, acc0[q]);
                acc1[q] = fmaf(xv1[k].x, wA[q].x, acc1[q]);
                acc1[q] = fmaf(xv1[k].y, wA[q].y, acc1[q]);
                acc1[q] = fmaf(xv1[k].z, wA[q].z, acc1[q]);
                acc1[q] = fmaf(xv1[k].w, wA[q].w, acc1[q]);
            }
            float4 wB[5];
            #pragma unroll
            for (int q = 0; q < 5; ++q) wB[q] = w1v[(5 + q) * 256 + k * 32 + o];
            #pragma unroll
            for (int q = 0; q < 5; ++q) {
                acc0[5+q] = fmaf(xv0[k].x, wB[q].x, acc0[5+q]);
                acc0[5+q] = fmaf(xv0[k].y, wB[q].y, acc0[5+q]);
                acc0[5+q] = fmaf(xv0[k].z, wB[q].z, acc0[5+q]);
                acc0[5+q] = fmaf(xv0[k].w, wB[q].w, acc0[5+q]);
                acc1[5+q] = fmaf(xv1[k].x, wB[q].x, acc1[5+q]);
                acc1[5+q] = fmaf(xv1[k].y, wB[q].y, acc1[5+q]);
                acc1[5+q] = fmaf(xv1[k].z, wB[q].z, acc1[5+q]);
                acc1[5+q] = fmaf(xv1[k].w, wB[q].w, acc1[5+q]);
            }
        }

        // DPP reduce over 32 lanes of each group (VALU pipe)
        #pragma unroll
        for (int q = 0; q < NQ; ++q) {
            acc0[q] = red32(acc0[q]);
            acc1[q] = red32(acc1[q]);
        }

        if (o == 16) {
            #pragma unroll
            for (int w = 0; w < NQ; ++w) {
                const float A = acc0[w] + b1q[w];
                sCA[rloc0][w] = __cosf(A);
                sSA[rloc0][w] = __sinf(A);
            }
        } else if (o == 17) {
            #pragma unroll
            for (int w = 0; w < NQ; ++w) {
                const float A = acc1[w] + b1q[w];
                sCA[rloc0 + 1][w] = __cosf(A);
                sSA[rloc0 + 1][w] = __sinf(A);
            }
        }
    }

    // ---- W2/b2 prefetch (latency hides under barrier + ev phase) ----
    const int e4 = tid & 255;
    float w2f[40];
    {
        const float4* w2v = (const float4*)(W2 + e4 * 40);
        #pragma unroll
        for (int i = 0; i < 10; ++i) {
            float4 v = w2v[i];
            w2f[4*i+0] = v.x; w2f[4*i+1] = v.y; w2f[4*i+2] = v.z; w2f[4*i+3] = v.w;
        }
    }
    const float4 b2v = ((const float4*)b2)[e4];

    __syncthreads();

    // ---------- ev: lane = row, wave-uniform q-set per wave ----------
    if (lane < ROWS_PER_BLOCK) {
        const int row = lane;
        float ca[NQ], sa[NQ], cb[NQ], sb[NQ];
        #pragma unroll
        for (int w = 0; w < NQ; ++w) {
            ca[w] = sCA[row][w];
            sa[w] = sSA[row][w];
            const float B = qw[NQ + w];
            cb[w] = __cosf(B); sb[w] = __sinf(B);
        }
        #define EVQ(QC) do {                                                      \
            float ev = 0.f;                                                       \
            _Pragma("unroll")                                                     \
            for (int k = 0; k < TT.nt[QC]; ++k) {                                 \
                float P = TT.sg[QC][k];                                           \
                _Pragma("unroll")                                                 \
                for (int w = 0; w < NQ; ++w) {                                    \
                    if ((TT.vm[QC] >> w) & 1) P *= ((TT.tm[QC][k] >> w) & 1) ? sa[w] : ca[w]; \
                    if ((TT.um[QC] >> w) & 1) P *= ((TT.sm[QC][k] >> w) & 1) ? sb[w] : cb[w]; \
                }                                                                 \
                ev += P;                                                          \
            }                                                                     \
            sEVv[row][QC] = ev;                                                   \
        } while (0)
        switch (wv) {
            case 0: EVQ(0); break;
            case 1: EVQ(9); break;
            case 2: EVQ(7); break;
            case 3: EVQ(8); break;
            case 4: EVQ(5); EVQ(6); break;
            case 5: EVQ(3); EVQ(4); break;
            case 6: EVQ(1); EVQ(2); break;
            default: break;              // wave 7 idle
        }
        #undef EVQ
    }

    __syncthreads();

    // ---------- stage 3: out[r][e] = b2[e] + sum_q ev[r][q]*W2[e][q] --------
    const int r0 = (tid >> 8) * 16;
    #pragma unroll
    for (int r = 0; r < 16; ++r) {
        const int rr = r0 + r;
        float evr[NQ];
        #pragma unroll
        for (int q = 0; q < NQ; ++q) evr[q] = sEVv[rr][q];
        float o0 = b2v.x, o1 = b2v.y, o2 = b2v.z, o3 = b2v.w;
        #pragma unroll
        for (int q = 0; q < NQ; ++q) {
            o0 = fmaf(evr[q], w2f[ 0 + q], o0);
            o1 = fmaf(evr[q], w2f[10 + q], o1);
            o2 = fmaf(evr[q], w2f[20 + q], o2);
            o3 = fmaf(evr[q], w2f[30 + q], o3);
        }
        float4 ov = {o0, o1, o2, o3};
        ((float4*)(out + (size_t)(block0 + rr) * EMBED))[e4] = ov;
    }
}

extern "C" void kernel_launch(void* const* d_in, const int* in_sizes, int n_in,
                              void* d_out, int out_size, void* d_ws, size_t ws_size,
                              hipStream_t stream) {
    (void)in_sizes; (void)n_in; (void)d_ws; (void)ws_size; (void)out_size;
    const float* x  = (const float*)d_in[0];
    const float* W1 = (const float*)d_in[1];
    const float* b1 = (const float*)d_in[2];
    const float* qw = (const float*)d_in[3];
    const float* W2 = (const float*)d_in[4];
    const float* b2 = (const float*)d_in[5];
    float* out = (float*)d_out;

    const int total_rows = 16 * 1024;
    dim3 grid(total_rows / ROWS_PER_BLOCK);   // 512 blocks, 2/CU, 16 waves/CU
    ffq_kernel<<<grid, BLOCK, 0, stream>>>(x, W1, b1, qw, W2, b2, out);
}